// Round 16
// baseline (590.967 us; speedup 1.0000x reference)
//
#include <hip/hip_runtime.h>
#include <hip/hip_bf16.h>

#define DDIM 128

typedef float    f32x16 __attribute__((ext_vector_type(16)));
typedef float    f32x4  __attribute__((ext_vector_type(4)));
typedef short    bf16x8 __attribute__((ext_vector_type(8)));
typedef __bf16   bf16x2t __attribute__((ext_vector_type(2)));
typedef unsigned u32x2  __attribute__((ext_vector_type(2)));
typedef unsigned u32x4  __attribute__((ext_vector_type(4)));
typedef unsigned short us4 __attribute__((ext_vector_type(4)));
typedef unsigned short us8 __attribute__((ext_vector_type(8)));

__device__ __forceinline__ unsigned pkbf(float a, float b) {
    bf16x2t v; v[0] = (__bf16)a; v[1] = (__bf16)b;
    return __builtin_bit_cast(unsigned, v);
}

__device__ __forceinline__ short f2bf16s(float a) {
    __bf16 b = (__bf16)a;
    return __builtin_bit_cast(short, b);
}

__device__ __forceinline__ float bf16tof(unsigned short u) {
    return __builtin_bit_cast(float, ((unsigned)u) << 16);
}

__device__ __forceinline__ bf16x8 cvt8(f32x4 a, f32x4 b) {
    u32x4 u = { pkbf(a[0],a[1]), pkbf(a[2],a[3]), pkbf(b[0],b[1]), pkbf(b[2],b[3]) };
    return __builtin_bit_cast(bf16x8, u);
}

__device__ __forceinline__ void plswap(unsigned &x, unsigned &y) {
    u32x2 r = __builtin_amdgcn_permlane32_swap(x, y, false, false);
    x = r[0]; y = r[1];
}

__device__ __forceinline__ float silu(float x) {
    return x * __builtin_amdgcn_rcpf(1.0f + __expf(-x));
}

// ---- kernel 0: FRAGMENT-MAJOR bf16 weights (layout verified R2-R15).
__global__ void prep_weights(const float* __restrict__ we, const float* __restrict__ wsrc,
                             const float* __restrict__ wdst, const float* __restrict__ wout,
                             short* __restrict__ w1frag, short* __restrict__ w2frag) {
    int tid = blockIdx.x * 256 + threadIdx.x;        // 65536 total
    if (tid < 24 * 128 * 16) {
        int k8 = tid & 7;
        int hi = (tid >> 3) & 1;
        int n  = (tid >> 4) & 127;
        int s  = tid >> 11;
        int col = 16 * s + 8 * hi + k8;              // 0..383
        const float* src = (col < 128) ? we : ((col < 256) ? wsrc : wdst);
        w1frag[tid] = f2bf16s(src[n * 128 + (col & 127)]);
    } else {
        int t2 = tid - 24 * 128 * 16;
        int k8 = t2 & 7;
        int hi = (t2 >> 3) & 1;
        int n  = (t2 >> 4) & 127;
        int s  = t2 >> 11;
        int col = 16 * s + 8 * hi + k8;              // 0..127
        w2frag[t2] = f2bf16s(wout[n * 128 + col]);
    }
}

// ---- node-table kernel (R12-verified): weight slice staged in LDS.
__global__ __launch_bounds__(256, 4) void node_table(
    const float* __restrict__ feat, const short* __restrict__ w1frag,
    int segoff, short* __restrict__ tbl, int N)
{
    __shared__ __align__(16) short wl[16384];        // 32 KB: this segment's 8 K-steps

    const int tid  = threadIdx.x;
    {
        const us8* s1 = (const us8*)(w1frag + segoff * 2048);
        us8* d1 = (us8*)wl;
        for (int i = tid; i < 2048; i += 256) d1[i] = s1[i];
    }
    __syncthreads();

    const int wave = tid >> 6;
    const int lane = tid & 63;
    const int lo   = lane & 31;
    const int hi   = lane >> 5;
    const int base = blockIdx.x * 128 + wave * 32;
    const int row  = base + lo;
    const int rcl  = row < N ? row : N - 1;
    const float* pn = feat + (size_t)rcl * DDIM;
    const int coff  = 8 * hi;
    const int fslot = (lo * 2 + hi) * 8;

    f32x4 fa[8], fb[8];
#pragma unroll
    for (int s = 0; s < 8; ++s) {
        const f32x4* pv = (const f32x4*)(pn + 16 * s + coff);
        fa[s] = pv[0];
        fb[s] = pv[1];
    }

    f32x16 acc[4];
#pragma unroll
    for (int t = 0; t < 4; ++t)
#pragma unroll
        for (int r = 0; r < 16; ++r) acc[t][r] = 0.0f;

#pragma unroll
    for (int s = 0; s < 8; ++s) {
        bf16x8 a = cvt8(fa[s], fb[s]);
        const short* wb = wl + s * 2048 + fslot;
#pragma unroll
        for (int t = 0; t < 4; ++t) {
            bf16x8 w = *(const bf16x8*)(wb + t * 512);
            acc[t] = __builtin_amdgcn_mfma_f32_32x32x16_bf16(a, w, acc[t], 0, 0, 0);
        }
    }

#pragma unroll
    for (int r = 0; r < 16; ++r) {
        const int m = (r & 3) + 8 * (r >> 2) + 4 * hi;
        const int node = base + m;
        if (node < N) {
            short* po = tbl + (size_t)node * DDIM;
#pragma unroll
            for (int t = 0; t < 4; ++t)
                po[32 * t + lo] = f2bf16s(acc[t][r]);
        }
    }
}

// ---- R16: R15 kernel verbatim, but __launch_bounds__(256,2) + 1024 blocks.
// R15 measured 212 VGPR spill-free, which fits the 256/wave budget of
// 2 waves/SIMD -> 2 resident blocks/CU = 8 waves/CU, each with the full
// 32KB/wave double-buffered prefetch. 2x the waves x depth product of R12/R15.
__global__ __launch_bounds__(256, 2) void edge_kernel_pipe(
    const float* __restrict__ efeat, const short* __restrict__ tsrc,
    const short* __restrict__ tdst, const int* __restrict__ src_idx,
    const int* __restrict__ dst_idx, const float* __restrict__ b0,
    const float* __restrict__ b_out, const float* __restrict__ ln_g,
    const float* __restrict__ ln_b, const short* __restrict__ w1frag,
    const short* __restrict__ w2frag, float* __restrict__ out, int E)
{
    __shared__ __align__(16) short wlds[32768];   // [0,16K): W_e frags  [16K,32K): W2 frags
    __shared__ __align__(16) float b0l[128], bol[128], gl[128], bl[128];

    const int tid = threadIdx.x;
    {
        const us8* s1 = (const us8*)w1frag;       // first 32 KB of w1frag = W_e slice (s=0..7)
        us8* d1 = (us8*)wlds;
        for (int i = tid; i < 2048; i += 256) d1[i] = s1[i];
        const us8* s2 = (const us8*)w2frag;
        us8* d2 = (us8*)(wlds + 16384);
        for (int i = tid; i < 2048; i += 256) d2[i] = s2[i];
        if (tid < 128) {
            b0l[tid] = b0[tid];  bol[tid] = b_out[tid];
            gl[tid]  = ln_g[tid]; bl[tid] = ln_b[tid];
        }
    }
    __syncthreads();

    const int lane = tid & 63;
    const int lo   = lane & 31;
    const int hi   = lane >> 5;
    const int coff  = 8 * hi;
    const int poff  = 4 * hi;
    const int fslot = (lo * 2 + hi) * 8;

    const int wave = tid >> 6;
    const int wid  = blockIdx.x * 4 + wave;
    const int nw   = gridDim.x * 4;
    int base = wid * 32;
    if (base >= E) return;
    const int stride = nw * 32;

    f32x4 faA[8], fbA[8], faB[8], fbB[8];
    us4  tsA[16], tdA[16], tsB[16], tdB[16];

    auto load_idx = [&](int tb, int& si, int& di) {
        int ec = tb + lo; if (ec >= E) ec = E - 1;
        si = src_idx[ec]; di = dst_idx[ec];
    };
    auto load_efeat = [&](int tb, f32x4 (&fa)[8], f32x4 (&fb)[8]) {
        int ec = tb + lo; if (ec >= E) ec = E - 1;
        const float* pe = efeat + (size_t)ec * DDIM;
#pragma unroll
        for (int s = 0; s < 8; ++s) {
            const f32x4* pv = (const f32x4*)(pe + 16 * s + coff);
            fa[s] = pv[0];
            fb[s] = pv[1];
        }
    };
    auto load_gather = [&](int si, int di, us4 (&ts)[16], us4 (&td)[16]) {
        const short* prs = tsrc + (size_t)si * DDIM;
        const short* prd = tdst + (size_t)di * DDIM;
#pragma unroll
        for (int t = 0; t < 4; ++t)
#pragma unroll
            for (int Q = 0; Q < 4; ++Q) {
                const int c = 32 * t + 8 * Q + poff;
                ts[t * 4 + Q] = *(const us4*)(prs + c);
                td[t * 4 + Q] = *(const us4*)(prd + c);
            }
    };

    auto do_tile = [&](int tb,
                       f32x4 (&fa)[8], f32x4 (&fb)[8], us4 (&ts)[16], us4 (&td)[16],
                       int nb,
                       f32x4 (&xfa)[8], f32x4 (&xfb)[8], us4 (&xts)[16], us4 (&xtd)[16],
                       bool pref) {
        // ---- prefetch next tile's idx + efeat (in flight through this tile) ----
        int nsi = 0, ndi = 0;
        if (pref) { load_idx(nb, nsi, ndi); load_efeat(nb, xfa, xfb); }

        // ---- GEMM1 (transposed): acc init from LDS b0 ----
        f32x16 acc[4];
#pragma unroll
        for (int t = 0; t < 4; ++t)
#pragma unroll
            for (int Q = 0; Q < 4; ++Q) {
                f32x4 bq = *(const f32x4*)(b0l + 32 * t + 8 * Q + poff);
                acc[t][4*Q+0] = bq[0]; acc[t][4*Q+1] = bq[1];
                acc[t][4*Q+2] = bq[2]; acc[t][4*Q+3] = bq[3];
            }

#pragma unroll
        for (int s = 0; s < 8; ++s) {
            bf16x8 x = cvt8(fa[s], fb[s]);               // B-frag: efeat[edge lo][16s+8hi+j]
            const short* wb = wlds + s * 2048 + fslot;   // A-frag from LDS (lgkmcnt)
#pragma unroll
            for (int t = 0; t < 4; ++t) {
                bf16x8 w = *(const bf16x8*)(wb + t * 512);
                acc[t] = __builtin_amdgcn_mfma_f32_32x32x16_bf16(w, x, acc[t], 0, 0, 0);
            }
        }

        // ---- prefetch next tile's gathers (idx had GEMM1 to land) ----
        if (pref) load_gather(nsi, ndi, xts, xtd);

        // ---- add gathered table rows (lane-local; c = 32t+8Q+4hi+j) ----
#pragma unroll
        for (int t = 0; t < 4; ++t)
#pragma unroll
            for (int Q = 0; Q < 4; ++Q) {
                us4 a = ts[t * 4 + Q], d = td[t * 4 + Q];
#pragma unroll
                for (int j = 0; j < 4; ++j)
                    acc[t][4*Q+j] += bf16tof(a[j]) + bf16tof(d[j]);
            }

        // ---- SiLU + pack to bf16, lane-local ----
        unsigned hbf[4][4][2];
#pragma unroll
        for (int t = 0; t < 4; ++t)
#pragma unroll
            for (int Q = 0; Q < 4; ++Q) {
                float h0 = silu(acc[t][4*Q+0]), h1 = silu(acc[t][4*Q+1]);
                float h2 = silu(acc[t][4*Q+2]), h3 = silu(acc[t][4*Q+3]);
                hbf[t][Q][0] = pkbf(h0, h1);
                hbf[t][Q][1] = pkbf(h2, h3);
            }

        // ---- GEMM2 (straight): weights from LDS ----
        f32x16 acc2[4];
#pragma unroll
        for (int tt = 0; tt < 4; ++tt) {
            float bv = bol[32 * tt + lo];
#pragma unroll
            for (int r = 0; r < 16; ++r) acc2[tt][r] = bv;
        }

#pragma unroll
        for (int s = 0; s < 8; ++s) {
            const int t  = s >> 1;
            const int q0 = (2 * s) & 3;
            const int q1 = q0 + 1;
            unsigned X0 = hbf[t][q0][0], X1 = hbf[t][q0][1];
            unsigned Y0 = hbf[t][q1][0], Y1 = hbf[t][q1][1];
            plswap(X0, Y0);
            plswap(X1, Y1);
            u32x4 fv = { X0, X1, Y0, Y1 };       // A-frag: h[edge lo][16s+8hi + 0..7]
            bf16x8 hf = __builtin_bit_cast(bf16x8, fv);
            const short* wb = wlds + 16384 + s * 2048 + fslot;
#pragma unroll
            for (int tt = 0; tt < 4; ++tt) {
                bf16x8 w = *(const bf16x8*)(wb + tt * 512);
                acc2[tt] = __builtin_amdgcn_mfma_f32_32x32x16_bf16(hf, w, acc2[tt], 0, 0, 0);
            }
        }

        // ---- LayerNorm (butterfly over 32 lanes) + coalesced store ----
        float gvw[4], bvw[4];
#pragma unroll
        for (int tt = 0; tt < 4; ++tt) {
            gvw[tt] = gl[32 * tt + lo];
            bvw[tt] = bl[32 * tt + lo];
        }

#pragma unroll
        for (int r = 0; r < 16; ++r) {
            float s1 = acc2[0][r] + acc2[1][r] + acc2[2][r] + acc2[3][r];
            float s2 = acc2[0][r]*acc2[0][r] + acc2[1][r]*acc2[1][r]
                     + acc2[2][r]*acc2[2][r] + acc2[3][r]*acc2[3][r];
#pragma unroll
            for (int msk = 1; msk < 32; msk <<= 1) {
                s1 += __shfl_xor(s1, msk, 64);
                s2 += __shfl_xor(s2, msk, 64);
            }
            const float mu   = s1 * (1.0f / 128.0f);
            const float var  = s2 * (1.0f / 128.0f) - mu * mu;
            const float rstd = rsqrtf(var + 1e-5f);
            const int   m    = (r & 3) + 8 * (r >> 2) + 4 * hi;
            const int   eo   = tb + m;
            if (eo < E) {
                float* po = out + (size_t)eo * DDIM;
#pragma unroll
                for (int tt = 0; tt < 4; ++tt) {
                    float o = (acc2[tt][r] - mu) * rstd * gvw[tt] + bvw[tt];
                    po[32 * tt + lo] = o;
                }
            }
        }
    };

    // prologue: fully load first tile into A
    {
        int si, di;
        load_idx(base, si, di);
        load_efeat(base, faA, fbA);
        load_gather(si, di, tsA, tdA);
    }

    int b = base;
    for (;;) {
        int nb = b + stride;
        do_tile(b, faA, fbA, tsA, tdA, nb, faB, fbB, tsB, tdB, nb < E);
        if (nb >= E) break;
        b = nb; nb = b + stride;
        do_tile(b, faB, fbB, tsB, tdB, nb, faA, fbA, tsA, tdA, nb < E);
        if (nb >= E) break;
        b = nb;
    }
}

// ---- deep fallback (R4-verified): full-K kernel, no workspace tables ----
__global__ __launch_bounds__(256, 4) void edge_kernel_fullk(
    const float* __restrict__ efeat, const float* __restrict__ src_feat,
    const float* __restrict__ dst_feat, const int* __restrict__ src_idx,
    const int* __restrict__ dst_idx, const float* __restrict__ b0,
    const float* __restrict__ b_out, const float* __restrict__ ln_g,
    const float* __restrict__ ln_b, const short* __restrict__ w1frag,
    const short* __restrict__ w2frag, float* __restrict__ out, int E)
{
    const int tid  = threadIdx.x;
    const int wave = tid >> 6;
    const int lane = tid & 63;
    const int lo   = lane & 31;
    const int hi   = lane >> 5;
    const int ebase = blockIdx.x * 128 + wave * 32;

    const int erow = ebase + lo;
    const int ecl  = erow < E ? erow : E - 1;
    const int sidx = src_idx[ecl];
    const int didx = dst_idx[ecl];
    const float* pe = efeat    + (size_t)ecl  * DDIM;
    const float* ps = src_feat + (size_t)sidx * DDIM;
    const float* pd = dst_feat + (size_t)didx * DDIM;

    const int coff  = 8 * hi;
    const int poff  = 4 * hi;
    const int fslot = (lo * 2 + hi) * 8;

    float bov[4], gv[4], bv[4];
#pragma unroll
    for (int tt = 0; tt < 4; ++tt) {
        int n = 32 * tt + lo;
        bov[tt] = b_out[n]; gv[tt] = ln_g[n]; bv[tt] = ln_b[n];
    }

    f32x16 acc[4];
#pragma unroll
    for (int t = 0; t < 4; ++t)
#pragma unroll
        for (int Q = 0; Q < 4; ++Q) {
            f32x4 bq = *(const f32x4*)(b0 + 32 * t + 8 * Q + poff);
            acc[t][4*Q+0] = bq[0]; acc[t][4*Q+1] = bq[1];
            acc[t][4*Q+2] = bq[2]; acc[t][4*Q+3] = bq[3];
        }

#pragma unroll
    for (int seg = 0; seg < 3; ++seg) {
        const float* p = (seg == 0) ? pe : ((seg == 1) ? ps : pd);
#pragma unroll
        for (int ks = 0; ks < 8; ++ks) {
            const f32x4* pv = (const f32x4*)(p + 16 * ks + coff);
            f32x4 fa = pv[0], fb = pv[1];
            bf16x8 x = cvt8(fa, fb);
            const int s = seg * 8 + ks;
            const short* wb = w1frag + s * 2048 + fslot;
#pragma unroll
            for (int t = 0; t < 4; ++t) {
                bf16x8 w = *(const bf16x8*)(wb + t * 512);
                acc[t] = __builtin_amdgcn_mfma_f32_32x32x16_bf16(w, x, acc[t], 0, 0, 0);
            }
        }
    }

    unsigned hbf[4][4][2];
#pragma unroll
    for (int t = 0; t < 4; ++t)
#pragma unroll
        for (int Q = 0; Q < 4; ++Q) {
            float h0 = silu(acc[t][4*Q+0]), h1 = silu(acc[t][4*Q+1]);
            float h2 = silu(acc[t][4*Q+2]), h3 = silu(acc[t][4*Q+3]);
            hbf[t][Q][0] = pkbf(h0, h1);
            hbf[t][Q][1] = pkbf(h2, h3);
        }

    f32x16 acc2[4];
#pragma unroll
    for (int tt = 0; tt < 4; ++tt)
#pragma unroll
        for (int r = 0; r < 16; ++r) acc2[tt][r] = bov[tt];

#pragma unroll
    for (int s = 0; s < 8; ++s) {
        const int t  = s >> 1;
        const int q0 = (2 * s) & 3;
        const int q1 = q0 + 1;
        unsigned X0 = hbf[t][q0][0], X1 = hbf[t][q0][1];
        unsigned Y0 = hbf[t][q1][0], Y1 = hbf[t][q1][1];
        plswap(X0, Y0);
        plswap(X1, Y1);
        u32x4 fv = { X0, X1, Y0, Y1 };
        bf16x8 hf = __builtin_bit_cast(bf16x8, fv);
        const short* wb = w2frag + s * 2048 + fslot;
#pragma unroll
        for (int tt = 0; tt < 4; ++tt) {
            bf16x8 w = *(const bf16x8*)(wb + tt * 512);
            acc2[tt] = __builtin_amdgcn_mfma_f32_32x32x16_bf16(hf, w, acc2[tt], 0, 0, 0);
        }
    }

#pragma unroll
    for (int r = 0; r < 16; ++r) {
        float s1 = acc2[0][r] + acc2[1][r] + acc2[2][r] + acc2[3][r];
        float s2 = acc2[0][r]*acc2[0][r] + acc2[1][r]*acc2[1][r]
                 + acc2[2][r]*acc2[2][r] + acc2[3][r]*acc2[3][r];
#pragma unroll
        for (int msk = 1; msk < 32; msk <<= 1) {
            s1 += __shfl_xor(s1, msk, 64);
            s2 += __shfl_xor(s2, msk, 64);
        }
        const float mu   = s1 * (1.0f / 128.0f);
        const float var  = s2 * (1.0f / 128.0f) - mu * mu;
        const float rstd = rsqrtf(var + 1e-5f);
        const int   m    = (r & 3) + 8 * (r >> 2) + 4 * hi;
        const int   eo   = ebase + m;
        if (eo < E) {
            float* po = out + (size_t)eo * DDIM;
#pragma unroll
            for (int tt = 0; tt < 4; ++tt) {
                float o = (acc2[tt][r] - mu) * rstd * gv[tt] + bv[tt];
                po[32 * tt + lo] = o;
            }
        }
    }
}

extern "C" void kernel_launch(void* const* d_in, const int* in_sizes, int n_in,
                              void* d_out, int out_size, void* d_ws, size_t ws_size,
                              hipStream_t stream)
{
    const float* efeat    = (const float*)d_in[0];
    const float* src_feat = (const float*)d_in[1];
    const float* dst_feat = (const float*)d_in[2];
    const int*   src_idx  = (const int*)d_in[3];
    const int*   dst_idx  = (const int*)d_in[4];
    const float* w_efeat  = (const float*)d_in[5];
    const float* w_src    = (const float*)d_in[6];
    const float* w_dst    = (const float*)d_in[7];
    const float* b0       = (const float*)d_in[8];
    const float* w_out    = (const float*)d_in[9];
    const float* b_out    = (const float*)d_in[10];
    const float* ln_g     = (const float*)d_in[11];
    const float* ln_b     = (const float*)d_in[12];
    float* out = (float*)d_out;
    const int E    = in_sizes[3];
    const int nsrc = in_sizes[1] / DDIM;
    const int ndst = in_sizes[2] / DDIM;

    short* w1frag = (short*)d_ws;                              // 96 KB
    short* w2frag = (short*)((char*)d_ws + 24 * 128 * 16 * 2); // 32 KB
    const size_t tab_off  = 128 * 1024;
    const size_t need_tab = tab_off + ((size_t)nsrc + (size_t)ndst) * DDIM * 2;

    prep_weights<<<256, 256, 0, stream>>>(w_efeat, w_src, w_dst, w_out, w1frag, w2frag);

    if (ws_size >= need_tab) {
        short* tsrc = (short*)((char*)d_ws + tab_off);
        short* tdst = tsrc + (size_t)nsrc * DDIM;
        node_table<<<(nsrc + 127) / 128, 256, 0, stream>>>(src_feat, w1frag, 8,  tsrc, nsrc);
        node_table<<<(ndst + 127) / 128, 256, 0, stream>>>(dst_feat, w1frag, 16, tdst, ndst);
        // persistent work-queue: 1024 blocks of 4 waves; 2 blocks/CU resident
        edge_kernel_pipe<<<1024, 256, 0, stream>>>(efeat, tsrc, tdst, src_idx, dst_idx,
                                                   b0, b_out, ln_g, ln_b, w1frag, w2frag, out, E);
    } else {
        const int nb = (E + 127) / 128;
        edge_kernel_fullk<<<nb, 256, 0, stream>>>(efeat, src_feat, dst_feat, src_idx, dst_idx,
                                                  b0, b_out, ln_g, ln_b, w1frag, w2frag, out, E);
    }
}

// Round 17
// 380.189 us; speedup vs baseline: 1.5544x; 1.5544x over previous
//
#include <hip/hip_runtime.h>
#include <hip/hip_bf16.h>

#define DDIM 128

typedef float    f32x16 __attribute__((ext_vector_type(16)));
typedef float    f32x4  __attribute__((ext_vector_type(4)));
typedef short    bf16x8 __attribute__((ext_vector_type(8)));
typedef __bf16   bf16x2t __attribute__((ext_vector_type(2)));
typedef unsigned u32x2  __attribute__((ext_vector_type(2)));
typedef unsigned u32x4  __attribute__((ext_vector_type(4)));
typedef unsigned short us4 __attribute__((ext_vector_type(4)));
typedef unsigned short us8 __attribute__((ext_vector_type(8)));

__device__ __forceinline__ unsigned pkbf(float a, float b) {
    bf16x2t v; v[0] = (__bf16)a; v[1] = (__bf16)b;
    return __builtin_bit_cast(unsigned, v);
}

__device__ __forceinline__ short f2bf16s(float a) {
    __bf16 b = (__bf16)a;
    return __builtin_bit_cast(short, b);
}

__device__ __forceinline__ float bf16tof(unsigned short u) {
    return __builtin_bit_cast(float, ((unsigned)u) << 16);
}

__device__ __forceinline__ bf16x8 cvt8(f32x4 a, f32x4 b) {
    u32x4 u = { pkbf(a[0],a[1]), pkbf(a[2],a[3]), pkbf(b[0],b[1]), pkbf(b[2],b[3]) };
    return __builtin_bit_cast(bf16x8, u);
}

__device__ __forceinline__ void plswap(unsigned &x, unsigned &y) {
    u32x2 r = __builtin_amdgcn_permlane32_swap(x, y, false, false);
    x = r[0]; y = r[1];
}

__device__ __forceinline__ float silu(float x) {
    return x * __builtin_amdgcn_rcpf(1.0f + __expf(-x));
}

// async 16B global->LDS (dest = wave-uniform base + lane*16) — verified R6
__device__ __forceinline__ void load_lds16(const void* g, void* l) {
    __builtin_amdgcn_global_load_lds(
        (const __attribute__((address_space(1))) void*)g,
        (__attribute__((address_space(3))) void*)l, 16, 0, 0);
}

// ---- kernel 0: FRAGMENT-MAJOR bf16 weights (layout verified R2-R16).
__global__ void prep_weights(const float* __restrict__ we, const float* __restrict__ wsrc,
                             const float* __restrict__ wdst, const float* __restrict__ wout,
                             short* __restrict__ w1frag, short* __restrict__ w2frag) {
    int tid = blockIdx.x * 256 + threadIdx.x;        // 65536 total
    if (tid < 24 * 128 * 16) {
        int k8 = tid & 7;
        int hi = (tid >> 3) & 1;
        int n  = (tid >> 4) & 127;
        int s  = tid >> 11;
        int col = 16 * s + 8 * hi + k8;              // 0..383
        const float* src = (col < 128) ? we : ((col < 256) ? wsrc : wdst);
        w1frag[tid] = f2bf16s(src[n * 128 + (col & 127)]);
    } else {
        int t2 = tid - 24 * 128 * 16;
        int k8 = t2 & 7;
        int hi = (t2 >> 3) & 1;
        int n  = (t2 >> 4) & 127;
        int s  = t2 >> 11;
        int col = 16 * s + 8 * hi + k8;              // 0..127
        w2frag[t2] = f2bf16s(wout[n * 128 + col]);
    }
}

// ---- node-table kernel (R12-verified): weight slice staged in LDS.
__global__ __launch_bounds__(256, 4) void node_table(
    const float* __restrict__ feat, const short* __restrict__ w1frag,
    int segoff, short* __restrict__ tbl, int N)
{
    __shared__ __align__(16) short wl[16384];        // 32 KB: this segment's 8 K-steps

    const int tid  = threadIdx.x;
    {
        const us8* s1 = (const us8*)(w1frag + segoff * 2048);
        us8* d1 = (us8*)wl;
        for (int i = tid; i < 2048; i += 256) d1[i] = s1[i];
    }
    __syncthreads();

    const int wave = tid >> 6;
    const int lane = tid & 63;
    const int lo   = lane & 31;
    const int hi   = lane >> 5;
    const int base = blockIdx.x * 128 + wave * 32;
    const int row  = base + lo;
    const int rcl  = row < N ? row : N - 1;
    const float* pn = feat + (size_t)rcl * DDIM;
    const int coff  = 8 * hi;
    const int fslot = (lo * 2 + hi) * 8;

    f32x4 fa[8], fb[8];
#pragma unroll
    for (int s = 0; s < 8; ++s) {
        const f32x4* pv = (const f32x4*)(pn + 16 * s + coff);
        fa[s] = pv[0];
        fb[s] = pv[1];
    }

    f32x16 acc[4];
#pragma unroll
    for (int t = 0; t < 4; ++t)
#pragma unroll
        for (int r = 0; r < 16; ++r) acc[t][r] = 0.0f;

#pragma unroll
    for (int s = 0; s < 8; ++s) {
        bf16x8 a = cvt8(fa[s], fb[s]);
        const short* wb = wl + s * 2048 + fslot;
#pragma unroll
        for (int t = 0; t < 4; ++t) {
            bf16x8 w = *(const bf16x8*)(wb + t * 512);
            acc[t] = __builtin_amdgcn_mfma_f32_32x32x16_bf16(a, w, acc[t], 0, 0, 0);
        }
    }

#pragma unroll
    for (int r = 0; r < 16; ++r) {
        const int m = (r & 3) + 8 * (r >> 2) + 4 * hi;
        const int node = base + m;
        if (node < N) {
            short* po = tbl + (size_t)node * DDIM;
#pragma unroll
            for (int t = 0; t < 4; ++t)
                po[32 * t + lo] = f2bf16s(acc[t][r]);
        }
    }
}

// ---- R17: persistent edge kernel with DMA efeat staging (zero-VGPR prefetch).
// LDS: 64KB weights + 2KB params + 4x16KB per-wave efeat tiles (130KB, 1 block/CU).
// vmcnt queue per wave: [16 DMA (oldest)] [32 gathers]; counted vmcnt(32) waits
// only the DMAs; gathers retire under GEMM1's MFMA; next-tile DMA issues after
// lgkmcnt(0) and flies under silu/GEMM2/LN/store.
__global__ __launch_bounds__(256, 1) void edge_kernel_dma(
    const float* __restrict__ efeat, const short* __restrict__ tsrc,
    const short* __restrict__ tdst, const int* __restrict__ src_idx,
    const int* __restrict__ dst_idx, const float* __restrict__ b0,
    const float* __restrict__ b_out, const float* __restrict__ ln_g,
    const float* __restrict__ ln_b, const short* __restrict__ w1frag,
    const short* __restrict__ w2frag, float* __restrict__ out, int E)
{
    __shared__ __align__(16) short wlds[32768];      // [0,16K): W_e frags  [16K,32K): W2 frags
    __shared__ __align__(16) float b0l[128], bol[128], gl[128], bl[128];
    __shared__ __align__(16) char  ebuf_all[4 * 16384];  // per-wave efeat tile (swizzled)

    const int tid = threadIdx.x;
    {
        const us8* s1 = (const us8*)w1frag;          // first 32 KB of w1frag = W_e slice (s=0..7)
        us8* d1 = (us8*)wlds;
        for (int i = tid; i < 2048; i += 256) d1[i] = s1[i];
        const us8* s2 = (const us8*)w2frag;
        us8* d2 = (us8*)(wlds + 16384);
        for (int i = tid; i < 2048; i += 256) d2[i] = s2[i];
        if (tid < 128) {
            b0l[tid] = b0[tid];  bol[tid] = b_out[tid];
            gl[tid]  = ln_g[tid]; bl[tid] = ln_b[tid];
        }
    }
    __syncthreads();

    const int wave = tid >> 6;
    const int lane = tid & 63;
    const int lo   = lane & 31;
    const int hi   = lane >> 5;
    const int poff  = 4 * hi;
    const int fslot = (lo * 2 + hi) * 8;
    const int xsw   = lo & 7;                    // LDS read swizzle for this lane's row

    char* ebuf = ebuf_all + wave * 16384;

    const int wid    = blockIdx.x * 4 + wave;
    const int nwaves = gridDim.x * 4;
    const int stride = nwaves * 32;
    int tb = wid * 32;
    if (tb >= E) return;                         // uniform per wave; after all barriers

    // ---- stage(t): 16 x 1KB DMA, source chunk XOR-pre-swizzled (R6-verified) ----
    // LDS[r*512 + 16*c] = efeat[row][chunk c ^ (r&7)] ; dest = ebuf + k*1024 (+lane*16 implicit)
    auto stage = [&](int t) {
#pragma unroll
        for (int k = 0; k < 16; ++k) {
            const int r  = 2 * k + hi;           // wave-local row 0..31
            const int cs = lo ^ (r & 7);         // swizzled source chunk
            int gr = t + r; if (gr >= E) gr = E - 1;
            const char* gp = (const char*)(efeat + (size_t)gr * DDIM) + cs * 16;
            load_lds16(gp, ebuf + k * 1024);
        }
    };

    // prologue: DMA first tile + its idx
    stage(tb);
    __builtin_amdgcn_sched_barrier(0);
    int ecl0 = tb + lo; if (ecl0 >= E) ecl0 = E - 1;
    int si = src_idx[ecl0];
    int di = dst_idx[ecl0];

    for (;;) {
        // ---- 1. issue this tile's 32 gathers (pinned between fences) ----
        __builtin_amdgcn_sched_barrier(0);
        const short* prs = tsrc + (size_t)si * DDIM;
        const short* prd = tdst + (size_t)di * DDIM;
        us4 tsv[16], tdv[16];
#pragma unroll
        for (int t = 0; t < 4; ++t)
#pragma unroll
            for (int Q = 0; Q < 4; ++Q) {
                const int c = 32 * t + 8 * Q + poff;
                tsv[t * 4 + Q] = *(const us4*)(prs + c);
                tdv[t * 4 + Q] = *(const us4*)(prd + c);
            }
        __builtin_amdgcn_sched_barrier(0);

        // ---- 2. wait ONLY the 16 DMAs (leave 32 gathers in flight) ----
        asm volatile("s_waitcnt vmcnt(32)" ::: "memory");
        __builtin_amdgcn_sched_barrier(0);

        // ---- 3. GEMM1 (transposed): efeat from LDS (swizzled), weights from LDS ----
        f32x16 acc[4];
#pragma unroll
        for (int t = 0; t < 4; ++t)
#pragma unroll
            for (int Q = 0; Q < 4; ++Q) {
                f32x4 bq = *(const f32x4*)(b0l + 32 * t + 8 * Q + poff);
                acc[t][4*Q+0] = bq[0]; acc[t][4*Q+1] = bq[1];
                acc[t][4*Q+2] = bq[2]; acc[t][4*Q+3] = bq[3];
            }

        const char* rb = ebuf + lo * 512;        // this lane's edge row
#pragma unroll
        for (int s = 0; s < 8; ++s) {
            const int g0 = 4 * s + 2 * hi;       // global 16B chunk index
            f32x4 fa = *(const f32x4*)(rb + 16 * ((g0    ) ^ xsw));
            f32x4 fb = *(const f32x4*)(rb + 16 * ((g0 + 1) ^ xsw));
            bf16x8 x = cvt8(fa, fb);             // B-frag: efeat[edge lo][16s+8hi+j]
            const short* wb = wlds + s * 2048 + fslot;
#pragma unroll
            for (int t = 0; t < 4; ++t) {
                bf16x8 w = *(const bf16x8*)(wb + t * 512);
                acc[t] = __builtin_amdgcn_mfma_f32_32x32x16_bf16(w, x, acc[t], 0, 0, 0);
            }
        }

        // ---- 4. drain ds_reads, then DMA next tile into the same buffer ----
        asm volatile("s_waitcnt lgkmcnt(0)" ::: "memory");
        __builtin_amdgcn_sched_barrier(0);
        const int nt = tb + stride;
        const bool hasnext = nt < E;
        if (hasnext) {
            stage(nt);
            int ecn = nt + lo; if (ecn >= E) ecn = E - 1;
            si = src_idx[ecn];
            di = dst_idx[ecn];
        }
        __builtin_amdgcn_sched_barrier(0);

        // ---- 5. add gathered table rows (compiler waits gathers; DMA stays in flight) ----
#pragma unroll
        for (int t = 0; t < 4; ++t)
#pragma unroll
            for (int Q = 0; Q < 4; ++Q) {
                us4 a = tsv[t * 4 + Q], d = tdv[t * 4 + Q];
#pragma unroll
                for (int j = 0; j < 4; ++j)
                    acc[t][4*Q+j] += bf16tof(a[j]) + bf16tof(d[j]);
            }

        // ---- 6. SiLU + pack ----
        unsigned hbf[4][4][2];
#pragma unroll
        for (int t = 0; t < 4; ++t)
#pragma unroll
            for (int Q = 0; Q < 4; ++Q) {
                float h0 = silu(acc[t][4*Q+0]), h1 = silu(acc[t][4*Q+1]);
                float h2 = silu(acc[t][4*Q+2]), h3 = silu(acc[t][4*Q+3]);
                hbf[t][Q][0] = pkbf(h0, h1);
                hbf[t][Q][1] = pkbf(h2, h3);
            }

        // ---- 7. GEMM2 (straight): weights from LDS ----
        f32x16 acc2[4];
#pragma unroll
        for (int tt = 0; tt < 4; ++tt) {
            float bv = bol[32 * tt + lo];
#pragma unroll
            for (int r = 0; r < 16; ++r) acc2[tt][r] = bv;
        }

#pragma unroll
        for (int s = 0; s < 8; ++s) {
            const int t  = s >> 1;
            const int q0 = (2 * s) & 3;
            const int q1 = q0 + 1;
            unsigned X0 = hbf[t][q0][0], X1 = hbf[t][q0][1];
            unsigned Y0 = hbf[t][q1][0], Y1 = hbf[t][q1][1];
            plswap(X0, Y0);
            plswap(X1, Y1);
            u32x4 fv = { X0, X1, Y0, Y1 };       // A-frag: h[edge lo][16s+8hi + 0..7]
            bf16x8 hf = __builtin_bit_cast(bf16x8, fv);
            const short* wb = wlds + 16384 + s * 2048 + fslot;
#pragma unroll
            for (int tt = 0; tt < 4; ++tt) {
                bf16x8 w = *(const bf16x8*)(wb + tt * 512);
                acc2[tt] = __builtin_amdgcn_mfma_f32_32x32x16_bf16(hf, w, acc2[tt], 0, 0, 0);
            }
        }

        // ---- 8. LayerNorm + coalesced store ----
        float gvw[4], bvw[4];
#pragma unroll
        for (int tt = 0; tt < 4; ++tt) {
            gvw[tt] = gl[32 * tt + lo];
            bvw[tt] = bl[32 * tt + lo];
        }

#pragma unroll
        for (int r = 0; r < 16; ++r) {
            float s1 = acc2[0][r] + acc2[1][r] + acc2[2][r] + acc2[3][r];
            float s2 = acc2[0][r]*acc2[0][r] + acc2[1][r]*acc2[1][r]
                     + acc2[2][r]*acc2[2][r] + acc2[3][r]*acc2[3][r];
#pragma unroll
            for (int msk = 1; msk < 32; msk <<= 1) {
                s1 += __shfl_xor(s1, msk, 64);
                s2 += __shfl_xor(s2, msk, 64);
            }
            const float mu   = s1 * (1.0f / 128.0f);
            const float var  = s2 * (1.0f / 128.0f) - mu * mu;
            const float rstd = rsqrtf(var + 1e-5f);
            const int   m    = (r & 3) + 8 * (r >> 2) + 4 * hi;
            const int   eo   = tb + m;
            if (eo < E) {
                float* po = out + (size_t)eo * DDIM;
#pragma unroll
                for (int tt = 0; tt < 4; ++tt) {
                    float o = (acc2[tt][r] - mu) * rstd * gvw[tt] + bvw[tt];
                    po[32 * tt + lo] = o;
                }
            }
        }

        if (!hasnext) break;
        tb = nt;
    }
}

// ---- deep fallback (R4-verified): full-K kernel, no workspace tables ----
__global__ __launch_bounds__(256, 4) void edge_kernel_fullk(
    const float* __restrict__ efeat, const float* __restrict__ src_feat,
    const float* __restrict__ dst_feat, const int* __restrict__ src_idx,
    const int* __restrict__ dst_idx, const float* __restrict__ b0,
    const float* __restrict__ b_out, const float* __restrict__ ln_g,
    const float* __restrict__ ln_b, const short* __restrict__ w1frag,
    const short* __restrict__ w2frag, float* __restrict__ out, int E)
{
    const int tid  = threadIdx.x;
    const int wave = tid >> 6;
    const int lane = tid & 63;
    const int lo   = lane & 31;
    const int hi   = lane >> 5;
    const int ebase = blockIdx.x * 128 + wave * 32;

    const int erow = ebase + lo;
    const int ecl  = erow < E ? erow : E - 1;
    const int sidx = src_idx[ecl];
    const int didx = dst_idx[ecl];
    const float* pe = efeat    + (size_t)ecl  * DDIM;
    const float* ps = src_feat + (size_t)sidx * DDIM;
    const float* pd = dst_feat + (size_t)didx * DDIM;

    const int coff  = 8 * hi;
    const int poff  = 4 * hi;
    const int fslot = (lo * 2 + hi) * 8;

    float bov[4], gv[4], bv[4];
#pragma unroll
    for (int tt = 0; tt < 4; ++tt) {
        int n = 32 * tt + lo;
        bov[tt] = b_out[n]; gv[tt] = ln_g[n]; bv[tt] = ln_b[n];
    }

    f32x16 acc[4];
#pragma unroll
    for (int t = 0; t < 4; ++t)
#pragma unroll
        for (int Q = 0; Q < 4; ++Q) {
            f32x4 bq = *(const f32x4*)(b0 + 32 * t + 8 * Q + poff);
            acc[t][4*Q+0] = bq[0]; acc[t][4*Q+1] = bq[1];
            acc[t][4*Q+2] = bq[2]; acc[t][4*Q+3] = bq[3];
        }

#pragma unroll
    for (int seg = 0; seg < 3; ++seg) {
        const float* p = (seg == 0) ? pe : ((seg == 1) ? ps : pd);
#pragma unroll
        for (int ks = 0; ks < 8; ++ks) {
            const f32x4* pv = (const f32x4*)(p + 16 * ks + coff);
            f32x4 fa = pv[0], fb = pv[1];
            bf16x8 x = cvt8(fa, fb);
            const int s = seg * 8 + ks;
            const short* wb = w1frag + s * 2048 + fslot;
#pragma unroll
            for (int t = 0; t < 4; ++t) {
                bf16x8 w = *(const bf16x8*)(wb + t * 512);
                acc[t] = __builtin_amdgcn_mfma_f32_32x32x16_bf16(w, x, acc[t], 0, 0, 0);
            }
        }
    }

    unsigned hbf[4][4][2];
#pragma unroll
    for (int t = 0; t < 4; ++t)
#pragma unroll
        for (int Q = 0; Q < 4; ++Q) {
            float h0 = silu(acc[t][4*Q+0]), h1 = silu(acc[t][4*Q+1]);
            float h2 = silu(acc[t][4*Q+2]), h3 = silu(acc[t][4*Q+3]);
            hbf[t][Q][0] = pkbf(h0, h1);
            hbf[t][Q][1] = pkbf(h2, h3);
        }

    f32x16 acc2[4];
#pragma unroll
    for (int tt = 0; tt < 4; ++tt)
#pragma unroll
        for (int r = 0; r < 16; ++r) acc2[tt][r] = bov[tt];

#pragma unroll
    for (int s = 0; s < 8; ++s) {
        const int t  = s >> 1;
        const int q0 = (2 * s) & 3;
        const int q1 = q0 + 1;
        unsigned X0 = hbf[t][q0][0], X1 = hbf[t][q0][1];
        unsigned Y0 = hbf[t][q1][0], Y1 = hbf[t][q1][1];
        plswap(X0, Y0);
        plswap(X1, Y1);
        u32x4 fv = { X0, X1, Y0, Y1 };
        bf16x8 hf = __builtin_bit_cast(bf16x8, fv);
        const short* wb = w2frag + s * 2048 + fslot;
#pragma unroll
        for (int tt = 0; tt < 4; ++tt) {
            bf16x8 w = *(const bf16x8*)(wb + tt * 512);
            acc2[tt] = __builtin_amdgcn_mfma_f32_32x32x16_bf16(hf, w, acc2[tt], 0, 0, 0);
        }
    }

#pragma unroll
    for (int r = 0; r < 16; ++r) {
        float s1 = acc2[0][r] + acc2[1][r] + acc2[2][r] + acc2[3][r];
        float s2 = acc2[0][r]*acc2[0][r] + acc2[1][r]*acc2[1][r]
                 + acc2[2][r]*acc2[2][r] + acc2[3][r]*acc2[3][r];
#pragma unroll
        for (int msk = 1; msk < 32; msk <<= 1) {
            s1 += __shfl_xor(s1, msk, 64);
            s2 += __shfl_xor(s2, msk, 64);
        }
        const float mu   = s1 * (1.0f / 128.0f);
        const float var  = s2 * (1.0f / 128.0f) - mu * mu;
        const float rstd = rsqrtf(var + 1e-5f);
        const int   m    = (r & 3) + 8 * (r >> 2) + 4 * hi;
        const int   eo   = ebase + m;
        if (eo < E) {
            float* po = out + (size_t)eo * DDIM;
#pragma unroll
            for (int tt = 0; tt < 4; ++tt) {
                float o = (acc2[tt][r] - mu) * rstd * gv[tt] + bv[tt];
                po[32 * tt + lo] = o;
            }
        }
    }
}

extern "C" void kernel_launch(void* const* d_in, const int* in_sizes, int n_in,
                              void* d_out, int out_size, void* d_ws, size_t ws_size,
                              hipStream_t stream)
{
    const float* efeat    = (const float*)d_in[0];
    const float* src_feat = (const float*)d_in[1];
    const float* dst_feat = (const float*)d_in[2];
    const int*   src_idx  = (const int*)d_in[3];
    const int*   dst_idx  = (const int*)d_in[4];
    const float* w_efeat  = (const float*)d_in[5];
    const float* w_src    = (const float*)d_in[6];
    const float* w_dst    = (const float*)d_in[7];
    const float* b0       = (const float*)d_in[8];
    const float* w_out    = (const float*)d_in[9];
    const float* b_out    = (const float*)d_in[10];
    const float* ln_g     = (const float*)d_in[11];
    const float* ln_b     = (const float*)d_in[12];
    float* out = (float*)d_out;
    const int E    = in_sizes[3];
    const int nsrc = in_sizes[1] / DDIM;
    const int ndst = in_sizes[2] / DDIM;

    short* w1frag = (short*)d_ws;                              // 96 KB
    short* w2frag = (short*)((char*)d_ws + 24 * 128 * 16 * 2); // 32 KB
    const size_t tab_off  = 128 * 1024;
    const size_t need_tab = tab_off + ((size_t)nsrc + (size_t)ndst) * DDIM * 2;

    prep_weights<<<256, 256, 0, stream>>>(w_efeat, w_src, w_dst, w_out, w1frag, w2frag);

    if (ws_size >= need_tab) {
        short* tsrc = (short*)((char*)d_ws + tab_off);
        short* tdst = tsrc + (size_t)nsrc * DDIM;
        node_table<<<(nsrc + 127) / 128, 256, 0, stream>>>(src_feat, w1frag, 8,  tsrc, nsrc);
        node_table<<<(ndst + 127) / 128, 256, 0, stream>>>(dst_feat, w1frag, 16, tdst, ndst);
        // persistent: 256 blocks (1/CU), 4 waves each, ~31 tiles per wave
        edge_kernel_dma<<<256, 256, 0, stream>>>(efeat, tsrc, tdst, src_idx, dst_idx,
                                                 b0, b_out, ln_g, ln_b, w1frag, w2frag, out, E);
    } else {
        const int nb = (E + 127) / 128;
        edge_kernel_fullk<<<nb, 256, 0, stream>>>(efeat, src_feat, dst_feat, src_idx, dst_idx,
                                                  b0, b_out, ln_g, ln_b, w1frag, w2frag, out, E);
    }
}